// Round 6
// baseline (170.719 us; speedup 1.0000x reference)
//
#include <hip/hip_runtime.h>
#include <math.h>

// Problem constants (reference: B=4, N=2048, TIMESTEPS=1000, speed=0.01)
#define TIMESTEPS 1000
constexpr int Bc  = 4;
constexpr int Nc  = 2048;
constexpr int EcI = Nc * (Nc - 1) / 2;   // 2,096,128 edges per batch
constexpr int EG  = EcI / 4;             // 524,032 groups of 4 per batch

typedef int   i4v __attribute__((ext_vector_type(4)));
typedef float f4v __attribute__((ext_vector_type(4)));
// q in the stream kernel is only 4B-aligned (packed triangle offset):
typedef float f4u __attribute__((ext_vector_type(4), aligned(4)));

// Fill the 6-entry constant table for batch timestep tb.
__device__ __forceinline__ void fill_tab(float* tabrow, int tb) {
    // Qt[k] built with ts=k+1: flip = 0.5*(1 - 0.98^(k+1))
    const float f_t = 0.5f * (1.0f - powf(0.98f, (float)(tb + 1)));
    const int   tpe = (tb == 0) ? TIMESTEPS : tb;     // Qt[t-1], wrap -1 -> 999
    const float f_p = 0.5f * (1.0f - powf(0.98f, (float)tpe));
    const float f0  = 0.01f;                          // Qt[0] flip
    const float omf_t = 1.0f - f_t;
    tabrow[0] = f_t;                                  // probs1 when a0==0
    tabrow[1] = omf_t;                                // probs1 when a0==1
    tabrow[2] = f0          * f_p          / omf_t;   // a0=0,x=0
    tabrow[3] = (1.0f - f0) * f_p          / f_t;     // a0=0,x=1
    tabrow[4] = f0          * (1.0f - f_p) / f_t;     // a0=1,x=0
    tabrow[5] = (1.0f - f0) * (1.0f - f_p) / omf_t;   // a0=1,x=1
}

// ---------------- Kernel A: triangle structure (round-5, control arm) --------
// Batches 0..1. Verified absmax=0 lineage; nt loads.
__global__ __launch_bounds__(256) void diff_loss_tri_kernel(
    const int* __restrict__ adj, const int* __restrict__ t,
    const float* __restrict__ u, const float* __restrict__ q,
    double* __restrict__ partials)
{
    __shared__ float tab[2][8];
    if (threadIdx.x < 2) fill_tab(tab[threadIdx.x], t[threadIdx.x]);
    __syncthreads();

    const int totalEG = 2 * EG;                // batches 0,1
    const int stride = gridDim.x * blockDim.x;
    double acc = 0.0;
    for (int g = blockIdx.x * blockDim.x + threadIdx.x; g < totalEG; g += stride) {
        int b  = (g >= EG) ? 1 : 0;
        int e0 = (g - b * EG) << 2;            // packed index, multiple of 4

        // invert triangular index: largest i with i*(i-1)/2 <= e0
        float sf = sqrtf((float)(8 * e0 + 1));     // 8*e0+1 < 2^24: exact
        int i = (int)((1.0f + sf) * 0.5f);
        if (i * (i - 1) / 2 > e0)  --i;
        if (i * (i + 1) / 2 <= e0) ++i;
        int j = e0 - i * (i - 1) / 2;              // 0 <= j < i

        float p0   = tab[b][0], p1   = tab[b][1];
        float qt00 = tab[b][2], qt01 = tab[b][3];
        float qt10 = tab[b][4], qt11 = tab[b][5];

        const f4v q4 = __builtin_nontemporal_load((const f4v*)(q + b * EcI + e0));
        const float qk[4] = {q4.x, q4.y, q4.z, q4.w};

        int ii = i, jj = j;
        float s = 0.0f;
        #pragma unroll
        for (int k = 0; k < 4; ++k) {
            bool adv = (jj >= ii);
            ii += adv;
            jj = adv ? 0 : jj;
            int base = (b << 22) + (ii << 11) + jj;
            int   a0 = __builtin_nontemporal_load(adj + base);
            float uu = __builtin_nontemporal_load(u + base);
            float ps  = a0 ? p1 : p0;
            bool  x   = (uu < ps);
            float t0  = x ? qt01 : qt00;
            float t1  = x ? qt11 : qt10;
            float qtv = a0 ? t1 : t0;
            float qv  = qk[k];
            s += fmaxf(qv, 0.0f) - qv * qtv + __logf(1.0f + __expf(-fabsf(qv)));
            ++jj;
        }
        acc += (double)s;
    }

    for (int off = 32; off > 0; off >>= 1)
        acc += __shfl_down(acc, off, 64);
    __shared__ double wsum[4];
    int lane = threadIdx.x & 63, wid = threadIdx.x >> 6;
    if (lane == 0) wsum[wid] = acc;
    __syncthreads();
    if (threadIdx.x == 0)
        partials[blockIdx.x] = wsum[0] + wsum[1] + wsum[2] + wsum[3];
}

// ---------------- Kernel B: full-matrix pure stream (experiment arm) ---------
// Batches 2..3. Reads the ENTIRE adj/u matrices as row-aligned dwordx4 streams
// (upper triangle read and discarded -> perfect sequential pattern), masks the
// diagonal arithmetically. No sqrt, no scalar adj/u loads.
__global__ __launch_bounds__(256) void diff_loss_stream_kernel(
    const int* __restrict__ adj, const int* __restrict__ t,
    const float* __restrict__ u, const float* __restrict__ q,
    double* __restrict__ partials)
{
    __shared__ float tab[2][8];
    if (threadIdx.x < 2) fill_tab(tab[threadIdx.x], t[2 + threadIdx.x]);
    __syncthreads();

    const int totalC = 2 * (Nc * Nc / 4);      // 2,097,152 chunks (16B each)
    const int stride = gridDim.x * blockDim.x;
    double acc = 0.0;
    for (int c = blockIdx.x * blockDim.x + threadIdx.x; c < totalC; c += stride) {
        const int b2  = c >> 20;                       // 0 or 1 (batch 2+b2)
        const int rem = c & ((Nc * Nc / 4) - 1);
        const int r   = rem >> 9;                      // row 0..2047
        const int j0  = (rem & 511) << 2;              // col, multiple of 4

        const size_t mbase = ((size_t)(2 + b2) << 22) + ((size_t)r << 11) + j0;
        const i4v a4 = __builtin_nontemporal_load((const i4v*)(adj + mbase));
        const f4v u4 = __builtin_nontemporal_load((const f4v*)(u + mbase));
        // Keep the stream alive when the chunk is fully above the diagonal
        // (rule: ablation-via-skip DCEs upstream-dead ops).
        asm volatile("" :: "v"(a4[0]), "v"(a4[1]), "v"(a4[2]), "v"(a4[3]),
                           "v"(u4[0]), "v"(u4[1]), "v"(u4[2]), "v"(u4[3]));
        if (j0 >= r) continue;                         // no lower-tri element here

        const float p0   = tab[b2][0], p1   = tab[b2][1];
        const float qt00 = tab[b2][2], qt01 = tab[b2][3];
        const float qt10 = tab[b2][4], qt11 = tab[b2][5];

        const int e = ((r * (r - 1)) >> 1) + j0;       // packed offset, row r
        const float* qb = q + (size_t)(2 + b2) * EcI;
        float qk[4];
        if (j0 + 4 <= r) {                             // whole chunk below diag
            const f4u q4 = __builtin_nontemporal_load((const f4u*)(qb + e));
            qk[0] = q4.x; qk[1] = q4.y; qk[2] = q4.z; qk[3] = q4.w;
        } else {                                       // diagonal straddle (rare)
            #pragma unroll
            for (int k = 0; k < 4; ++k)
                qk[k] = (j0 + k < r) ? __builtin_nontemporal_load(qb + e + k)
                                     : 0.0f;
        }

        float s = 0.0f;
        #pragma unroll
        for (int k = 0; k < 4; ++k) {
            const int   a0 = a4[k];
            const float ps = a0 ? p1 : p0;
            const bool  x  = u4[k] < ps;
            const float t0 = x ? qt01 : qt00;
            const float t1 = x ? qt11 : qt10;
            const float qtv = a0 ? t1 : t0;
            const float qv  = qk[k];
            const float term = fmaxf(qv, 0.0f) - qv * qtv
                             + __logf(1.0f + __expf(-fabsf(qv)));
            s += (j0 + k < r) ? term : 0.0f;           // diagonal mask
        }
        acc += (double)s;
    }

    for (int off = 32; off > 0; off >>= 1)
        acc += __shfl_down(acc, off, 64);
    __shared__ double wsum[4];
    int lane = threadIdx.x & 63, wid = threadIdx.x >> 6;
    if (lane == 0) wsum[wid] = acc;
    __syncthreads();
    if (threadIdx.x == 0)
        partials[1024 + blockIdx.x] = wsum[0] + wsum[1] + wsum[2] + wsum[3];
}

// Reduce per-block partials, write mean as f32.
__global__ __launch_bounds__(256) void final_reduce_kernel(
    const double* __restrict__ partials, int nb, float* __restrict__ out)
{
    double acc = 0.0;
    for (int idx = threadIdx.x; idx < nb; idx += blockDim.x)
        acc += partials[idx];
    for (int off = 32; off > 0; off >>= 1)
        acc += __shfl_down(acc, off, 64);
    __shared__ double wsum[4];
    int lane = threadIdx.x & 63, wid = threadIdx.x >> 6;
    if (lane == 0) wsum[wid] = acc;
    __syncthreads();
    if (threadIdx.x == 0)
        out[0] = (float)((wsum[0] + wsum[1] + wsum[2] + wsum[3]) /
                         ((double)Bc * (double)EcI));
}

extern "C" void kernel_launch(void* const* d_in, const int* in_sizes, int n_in,
                              void* d_out, int out_size, void* d_ws, size_t ws_size,
                              hipStream_t stream) {
    const int*   adj = (const int*)d_in[0];   // adj_start (B,N,N) int32
    const int*   t   = (const int*)d_in[1];   // t (B,) int32
    const float* u   = (const float*)d_in[2]; // u (B,N,N) f32
    const float* q   = (const float*)d_in[3]; // q_approx (B,E) f32
    float*  out      = (float*)d_out;
    double* partials = (double*)d_ws;         // 2048 doubles (16 KB)

    // Within-probe A/B: triangle structure on batches 0-1, pure-stream on 2-3.
    diff_loss_tri_kernel   <<<1024, 256, 0, stream>>>(adj, t, u, q, partials);
    diff_loss_stream_kernel<<<1024, 256, 0, stream>>>(adj, t, u, q, partials);
    final_reduce_kernel<<<1, 256, 0, stream>>>(partials, 2048, out);
}

// Round 7
// 156.681 us; speedup vs baseline: 1.0896x; 1.0896x over previous
//
#include <hip/hip_runtime.h>
#include <math.h>

// Problem constants (reference: B=4, N=2048, TIMESTEPS=1000, speed=0.01)
#define TIMESTEPS 1000
constexpr int Bc  = 4;
constexpr int Nc  = 2048;
constexpr int EcI = Nc * (Nc - 1) / 2;   // 2,096,128 edges per batch
constexpr int CHUNKS = Nc * Nc / 4;      // 1,048,576 16B row-chunks per batch

constexpr int BLKX    = 512;             // grid = (512, 4); 8 chunks/thread
constexpr int THREADS = 256;

typedef int   i4v __attribute__((ext_vector_type(4)));
typedef float f4v __attribute__((ext_vector_type(4)));
// q chunk start is tri(r)+j0: only 4B-aligned
typedef float f4u __attribute__((ext_vector_type(4), aligned(4)));

__device__ __forceinline__ int imin(int a, int b) { return a < b ? a : b; }

// Round-7: the round-6 B-arm (measured ~3.2 TB/s per touched byte, the best
// per-byte rate of any structure so far) applied to all 4 batches, minus the
// one thing that made it net-slower: loads for chunks fully above the diagonal
// are SKIPPED (they carried no information; only the lower triangle is used).
// Needed bytes: lower-tri adj + lower-tri u + q = 100.5 MB @ ~3.17 TB/s -> ~32 us.
__global__ __launch_bounds__(256) void diff_loss_kernel(
    const int* __restrict__ adj, const int* __restrict__ t,
    const float* __restrict__ u, const float* __restrict__ q,
    double* __restrict__ partials)
{
    const int b  = blockIdx.y;                 // batch (wave-uniform)
    const int tb = t[b];

    // Qt[k] built with ts=k+1: flip = 0.5*(1 - 0.98^(k+1))
    const float f_t   = 0.5f * (1.0f - powf(0.98f, (float)(tb + 1)));
    const int   tpe   = (tb == 0) ? TIMESTEPS : tb;   // Qt[t-1], wrap -1 -> 999
    const float f_p   = 0.5f * (1.0f - powf(0.98f, (float)tpe));
    const float f0    = 0.01f;                        // Qt[0] flip
    const float omf_t = 1.0f - f_t;

    const float p0   = f_t;                            // probs1 when a0==0
    const float p1   = omf_t;                          // probs1 when a0==1
    const float qt00 = f0          * f_p          / omf_t;  // a0=0,x=0
    const float qt01 = (1.0f - f0) * f_p          / f_t;    // a0=0,x=1
    const float qt10 = f0          * (1.0f - f_p) / f_t;    // a0=1,x=0
    const float qt11 = (1.0f - f0) * (1.0f - f_p) / omf_t;  // a0=1,x=1

    const int*   adjb = adj + ((size_t)b << 22);
    const float* ub   = u   + ((size_t)b << 22);
    const float* qb   = q   + (size_t)b * EcI;

    const int stride = BLKX * THREADS;         // 131,072 -> 8 iters/thread
    double acc = 0.0;

    for (int c = blockIdx.x * THREADS + threadIdx.x; c < CHUNKS; c += stride) {
        const int r  = c >> 9;                 // row 0..2047
        const int j0 = (c & 511) << 2;         // col, multiple of 4
        if (j0 >= r) continue;                 // chunk has no lower-tri element

        const int base = (r << 11) + j0;       // row-aligned, 16B-aligned
        const i4v a4 = __builtin_nontemporal_load((const i4v*)(adjb + base));
        const f4v u4 = __builtin_nontemporal_load((const f4v*)(ub   + base));

        const int e = ((r * (r - 1)) >> 1) + j0;   // packed q offset (24-bit mul)
        float qk[4];
        if (j0 + 4 <= r) {                     // whole chunk below diagonal
            const f4u q4 = __builtin_nontemporal_load((const f4u*)(qb + e));
            qk[0] = q4.x; qk[1] = q4.y; qk[2] = q4.z; qk[3] = q4.w;
        } else {                               // diagonal straddle (rare)
            #pragma unroll
            for (int k = 0; k < 4; ++k)
                qk[k] = __builtin_nontemporal_load(qb + e + imin(k, r - 1 - j0));
        }

        float s = 0.0f;
        #pragma unroll
        for (int k = 0; k < 4; ++k) {
            const int   a0 = a4[k];
            const float ps = a0 ? p1 : p0;
            const bool  x  = u4[k] < ps;
            const float t0 = x ? qt01 : qt00;
            const float t1 = x ? qt11 : qt10;
            const float qtv = a0 ? t1 : t0;
            const float qv  = qk[k];
            const float term = fmaxf(qv, 0.0f) - qv * qtv
                             + __logf(1.0f + __expf(-fabsf(qv)));
            s += (j0 + k < r) ? term : 0.0f;   // diagonal mask
        }
        acc += (double)s;
    }

    // wave (64) shuffle reduce, then cross-wave via LDS
    for (int off = 32; off > 0; off >>= 1)
        acc += __shfl_down(acc, off, 64);
    __shared__ double wsum[4];
    const int lane = threadIdx.x & 63, wid = threadIdx.x >> 6;
    if (lane == 0) wsum[wid] = acc;
    __syncthreads();
    if (threadIdx.x == 0)
        partials[blockIdx.y * BLKX + blockIdx.x] =
            wsum[0] + wsum[1] + wsum[2] + wsum[3];
}

// Reduce per-block partials, write mean as f32.
__global__ __launch_bounds__(256) void final_reduce_kernel(
    const double* __restrict__ partials, int nb, float* __restrict__ out)
{
    double acc = 0.0;
    for (int idx = threadIdx.x; idx < nb; idx += blockDim.x)
        acc += partials[idx];
    for (int off = 32; off > 0; off >>= 1)
        acc += __shfl_down(acc, off, 64);
    __shared__ double wsum[4];
    const int lane = threadIdx.x & 63, wid = threadIdx.x >> 6;
    if (lane == 0) wsum[wid] = acc;
    __syncthreads();
    if (threadIdx.x == 0)
        out[0] = (float)((wsum[0] + wsum[1] + wsum[2] + wsum[3]) /
                         ((double)Bc * (double)EcI));
}

extern "C" void kernel_launch(void* const* d_in, const int* in_sizes, int n_in,
                              void* d_out, int out_size, void* d_ws, size_t ws_size,
                              hipStream_t stream) {
    const int*   adj = (const int*)d_in[0];   // adj_start (B,N,N) int32
    const int*   t   = (const int*)d_in[1];   // t (B,) int32
    const float* u   = (const float*)d_in[2]; // u (B,N,N) f32
    const float* q   = (const float*)d_in[3]; // q_approx (B,E) f32
    float*  out      = (float*)d_out;
    double* partials = (double*)d_ws;         // 2048 doubles (16 KB)

    dim3 grid(BLKX, Bc);
    diff_loss_kernel<<<grid, THREADS, 0, stream>>>(adj, t, u, q, partials);
    final_reduce_kernel<<<1, 256, 0, stream>>>(partials, BLKX * Bc, out);
}